// Round 1
// baseline (184.889 us; speedup 1.0000x reference)
//
#include <hip/hip_runtime.h>

#define H_ 8
#define D_ 128
#define KD_ 16
#define E_ 128
#define B_ 16
#define G_ 501
#define NP_ 250
#define BN_ (B_*G_)   // 8016

typedef __bf16 bf16x8 __attribute__((ext_vector_type(8)));
typedef float f32x4 __attribute__((ext_vector_type(4)));
typedef unsigned short u16x4 __attribute__((ext_vector_type(4)));

__device__ __forceinline__ unsigned short f2bf(float f) {
  unsigned int u = __builtin_bit_cast(unsigned int, f);
  unsigned int r = u + 0x7FFFu + ((u >> 16) & 1u);
  return (unsigned short)(r >> 16);
}
__device__ __forceinline__ float bf2f(unsigned short u) {
  unsigned int v = ((unsigned int)u) << 16;
  return __builtin_bit_cast(float, v);
}

// ---------------- K0: cast q -> bf16, build WcT[c=(h,w,k)][d] bf16 ----------------
__global__ __launch_bounds__(256) void k_prep(
    const float* __restrict__ q,
    const float* __restrict__ w0, const float* __restrict__ w1, const float* __restrict__ w2,
    const float* __restrict__ w3, const float* __restrict__ w4, const float* __restrict__ w5,
    const float* __restrict__ w6, const float* __restrict__ w7, const float* __restrict__ w8,
    unsigned short* __restrict__ qb, unsigned short* __restrict__ wct) {
  int i = blockIdx.x * 256 + threadIdx.x;
  if (i < BN_*D_) qb[i] = f2bf(q[i]);
  if (i < H_*9*KD_*D_) {
    int d = i & 127; int t = i >> 7; int k = t & 15; t >>= 4;
    int wi = t % 9; int h = t / 9;
    const float* src = w0;
    switch (wi) {
      case 1: src = w1; break; case 2: src = w2; break; case 3: src = w3; break;
      case 4: src = w4; break; case 5: src = w5; break; case 6: src = w6; break;
      case 7: src = w7; break; case 8: src = w8; break; default: break;
    }
    wct[i] = f2bf(src[h*(D_*KD_) + d*KD_ + k]);
  }
}

// ---------------- K1: P[(h,w,b)][n][kd] = q @ Wcat, bf16 MFMA GEMM ----------------
__global__ __launch_bounds__(256) void k_proj(const unsigned short* __restrict__ qb,
                                              const unsigned short* __restrict__ wct,
                                              unsigned short* __restrict__ P) {
  const int tid = threadIdx.x;
  const int lane = tid & 63;
  const int wv = tid >> 6;
  const int ln = lane & 15;
  const int quad = lane >> 4;
  const int mblk = blockIdx.y;
  const int b = mblk >> 3;
  const int nt = mblk & 7;
  const int nbase = nt*64 + wv*16;
  const int nr = min(nbase + ln, G_ - 1);
  const unsigned short* qrow = qb + (size_t)(b*G_ + nr)*D_;
  bf16x8 a0 = *(const bf16x8*)(qrow +  0 + quad*8);
  bf16x8 a1 = *(const bf16x8*)(qrow + 32 + quad*8);
  bf16x8 a2 = *(const bf16x8*)(qrow + 64 + quad*8);
  bf16x8 a3 = *(const bf16x8*)(qrow + 96 + quad*8);
  const int cbase = blockIdx.x * 64;
  #pragma unroll
  for (int ct = 0; ct < 4; ++ct) {
    const int c = cbase + ct*16 + ln;
    const unsigned short* wrow = wct + (size_t)c*D_;
    f32x4 acc = {0.f,0.f,0.f,0.f};
    acc = __builtin_amdgcn_mfma_f32_16x16x32_bf16(a0, *(const bf16x8*)(wrow +  0 + quad*8), acc, 0,0,0);
    acc = __builtin_amdgcn_mfma_f32_16x16x32_bf16(a1, *(const bf16x8*)(wrow + 32 + quad*8), acc, 0,0,0);
    acc = __builtin_amdgcn_mfma_f32_16x16x32_bf16(a2, *(const bf16x8*)(wrow + 64 + quad*8), acc, 0,0,0);
    acc = __builtin_amdgcn_mfma_f32_16x16x32_bf16(a3, *(const bf16x8*)(wrow + 96 + quad*8), acc, 0,0,0);
    const int h = c / 144; const int rem = c - h*144; const int w = rem >> 4; const int k = rem & 15;
    const size_t pb = ((size_t)((h*9 + w)*B_ + b)*G_)*KD_ + k;
    #pragma unroll
    for (int g = 0; g < 4; ++g) {
      const int nn = nbase + quad*4 + g;
      if (nn < G_) P[pb + (size_t)nn*KD_] = f2bf(acc[g]);
    }
  }
}

// ---------------- K2: fused heterogeneous attention ----------------
// grid = (rt=8, b=16, h=8); block = 256 (4 waves x 16 rows)
__global__ __launch_bounds__(256) void k_attn(const unsigned short* __restrict__ P,
                                              float* __restrict__ heads) {
  const int rt = blockIdx.x, b = blockIdx.y, h = blockIdx.z;
  const int tid = threadIdx.x;
  const int lane = tid & 63;
  const int wv = tid >> 6;
  const int ln = lane & 15;
  const int quad = lane >> 4;
  const int r0 = rt * 64;

  __shared__ __align__(16) unsigned short sK[512*40];   // kd padded 16->32 zeros, stride 40
  __shared__ __align__(16) unsigned short sV[512*20];   // stride 20
  __shared__ __align__(16) unsigned short sQa[64*40];
  __shared__ __align__(16) unsigned short sQp[64*40];
  __shared__ __align__(16) unsigned short sQd[64*40];
  __shared__ __align__(16) unsigned short sQs[64*16];

  const size_t slab = (size_t)G_*KD_;
  const unsigned short* Pq = P + ((size_t)(h*9+0)*B_ + b)*slab;
  const unsigned short* Pk = P + ((size_t)(h*9+1)*B_ + b)*slab;
  const unsigned short* Pv = P + ((size_t)(h*9+2)*B_ + b)*slab;

  for (int i = tid; i < 512*16; i += 256) {
    int key = i >> 4, kd = i & 15;
    unsigned short kv = (key < G_) ? Pk[key*KD_ + kd] : (unsigned short)0;
    sK[key*40 + kd] = kv; sK[key*40 + 16 + kd] = 0;
    unsigned short vv = (key < G_) ? Pv[key*KD_ + kd] : (unsigned short)0;
    sV[key*20 + kd] = vv;
  }
  for (int i = tid; i < 64*16; i += 256) {
    int rr = i >> 4, kd = i & 15;
    int r = r0 + rr;
    bool ok = (r < G_);
    bool pick = (r <= NP_);
    int wp = pick ? 4 : 8;    // W2 : W6   (keys 1..250 stream)
    int wd = pick ? 5 : 7;    // W3 : W5   (keys 251..500 stream)
    int wsl = pick ? 3 : 6;   // W1 : W4   (single paired score)
    sQa[rr*40 + kd] = ok ? Pq[r*KD_ + kd] : (unsigned short)0;  sQa[rr*40+16+kd] = 0;
    sQp[rr*40 + kd] = ok ? P[((size_t)(h*9+wp)*B_ + b)*slab + r*KD_ + kd] : (unsigned short)0;  sQp[rr*40+16+kd] = 0;
    sQd[rr*40 + kd] = ok ? P[((size_t)(h*9+wd)*B_ + b)*slab + r*KD_ + kd] : (unsigned short)0;  sQd[rr*40+16+kd] = 0;
    sQs[rr*16 + kd] = ok ? P[((size_t)(h*9+wsl)*B_ + b)*slab + r*KD_ + kd] : (unsigned short)0;
  }
  __syncthreads();

  const int rw0 = r0 + wv*16;
  bf16x8 aQa = *(const bf16x8*)(sQa + (wv*16+ln)*40 + quad*8);
  bf16x8 aQp = *(const bf16x8*)(sQp + (wv*16+ln)*40 + quad*8);
  bf16x8 aQd = *(const bf16x8*)(sQd + (wv*16+ln)*40 + quad*8);

  float O[4][16];
  float esum[4] = {0.f,0.f,0.f,0.f};
  #pragma unroll
  for (int g = 0; g < 4; ++g)
    #pragma unroll
    for (int k = 0; k < 16; ++k) O[g][k] = 0.f;

  const f32x4 z4 = {0.f,0.f,0.f,0.f};
  for (int kt = 0; kt < 32; ++kt) {
    const int key = kt*16 + ln;
    bf16x8 bk = *(const bf16x8*)(sK + key*40 + quad*8);
    f32x4 sa = __builtin_amdgcn_mfma_f32_16x16x32_bf16(aQa, bk, z4, 0,0,0);
    f32x4 sp = __builtin_amdgcn_mfma_f32_16x16x32_bf16(aQp, bk, z4, 0,0,0);
    f32x4 sd = __builtin_amdgcn_mfma_f32_16x16x32_bf16(aQd, bk, z4, 0,0,0);

    float v[16];
    const unsigned short* vr = sV + key*20;
    u16x4 v0 = *(const u16x4*)(vr + 0);
    u16x4 v1 = *(const u16x4*)(vr + 4);
    u16x4 v2 = *(const u16x4*)(vr + 8);
    u16x4 v3 = *(const u16x4*)(vr + 12);
    #pragma unroll
    for (int j = 0; j < 4; ++j) {
      v[j] = bf2f(v0[j]); v[4+j] = bf2f(v1[j]); v[8+j] = bf2f(v2[j]); v[12+j] = bf2f(v3[j]);
    }
    const float va = (key < G_) ? 1.f : 0.f;
    const float vpm = (key >= 1 && key <= NP_) ? 1.f : 0.f;
    const float vdm = (key >= NP_+1 && key < G_) ? 1.f : 0.f;
    #pragma unroll
    for (int g = 0; g < 4; ++g) {
      const int r_abs = rw0 + quad*4 + g;
      const float rv = (r_abs >= 1) ? 1.f : 0.f;
      float ea = va        * __expf(fminf(0.25f * sa[g], 80.f));
      float ep = vpm * rv  * __expf(fminf(0.25f * sp[g], 80.f));
      float ed = vdm * rv  * __expf(fminf(0.25f * sd[g], 80.f));
      float et = ea + ep + ed;
      esum[g] += et;
      #pragma unroll
      for (int k = 0; k < 16; ++k) O[g][k] = fmaf(et, v[k], O[g][k]);
    }
  }

  // paired single score (one lane per quad does its 4 rows)
  if (ln == 0) {
    #pragma unroll
    for (int g = 0; g < 4; ++g) {
      const int r_abs = rw0 + quad*4 + g;
      if (r_abs >= 1 && r_abs < G_) {
        const int ks = (r_abs <= NP_) ? (r_abs + NP_) : (r_abs - NP_);
        const int rr = r_abs - r0;
        float s = 0.f;
        #pragma unroll
        for (int kd = 0; kd < 16; ++kd)
          s = fmaf(bf2f(sQs[rr*16+kd]), bf2f(sK[ks*40+kd]), s);
        float e = __expf(fminf(0.25f * s, 80.f));
        esum[g] += e;
        #pragma unroll
        for (int k = 0; k < 16; ++k) O[g][k] = fmaf(e, bf2f(sV[ks*20+k]), O[g][k]);
      }
    }
  }

  // butterfly reduce-scatter across the 16 lanes of each quad: lane ln ends with kd=ln
  #pragma unroll
  for (int g = 0; g < 4; ++g) {
    float c8[8], c4a[4], c2[2], c1;
    const bool s3 = (lane & 8) != 0;
    #pragma unroll
    for (int i = 0; i < 8; ++i) {
      float snd = s3 ? O[g][i] : O[g][i+8];
      float kp  = s3 ? O[g][i+8] : O[g][i];
      c8[i] = kp + __shfl_xor(snd, 8);
    }
    const bool s2 = (lane & 4) != 0;
    #pragma unroll
    for (int i = 0; i < 4; ++i) {
      float snd = s2 ? c8[i] : c8[i+4];
      float kp  = s2 ? c8[i+4] : c8[i];
      c4a[i] = kp + __shfl_xor(snd, 4);
    }
    const bool s1 = (lane & 2) != 0;
    #pragma unroll
    for (int i = 0; i < 2; ++i) {
      float snd = s1 ? c4a[i] : c4a[i+2];
      float kp  = s1 ? c4a[i+2] : c4a[i];
      c2[i] = kp + __shfl_xor(snd, 2);
    }
    {
      const bool s0 = (lane & 1) != 0;
      float snd = s0 ? c2[0] : c2[1];
      float kp  = s0 ? c2[1] : c2[0];
      c1 = kp + __shfl_xor(snd, 1);
    }
    float es = esum[g];
    es += __shfl_xor(es, 1); es += __shfl_xor(es, 2);
    es += __shfl_xor(es, 4); es += __shfl_xor(es, 8);
    const int r_abs = rw0 + quad*4 + g;
    if (r_abs < G_)
      heads[((size_t)(b*G_ + r_abs))*128 + h*16 + ln] = c1 / es;
  }
}

// ---------------- K3: out = heads(8016x128) @ W_out(128x128), fp32 ----------------
__global__ __launch_bounds__(256) void k_out(const float* __restrict__ heads,
                                             const float* __restrict__ wout,
                                             float* __restrict__ out) {
  const int base = blockIdx.x * 32;
  const int tid = threadIdx.x;
  __shared__ __align__(16) float sA[32*128];
  for (int i = tid; i < 32*32; i += 256) {
    int row = i >> 5, c4 = i & 31;
    int g = base + row;
    float4 val = (g < BN_) ? ((const float4*)heads)[(size_t)g*32 + c4]
                           : make_float4(0.f,0.f,0.f,0.f);
    ((float4*)sA)[row*32 + c4] = val;
  }
  __syncthreads();
  const int cg = tid & 31, rg = tid >> 5;
  float acc[4][4];
  #pragma unroll
  for (int i = 0; i < 4; ++i)
    #pragma unroll
    for (int j = 0; j < 4; ++j) acc[i][j] = 0.f;
  const float4* w4 = (const float4*)wout;
  for (int kk = 0; kk < 128; ++kk) {
    float4 wv = w4[kk*32 + cg];
    #pragma unroll
    for (int i = 0; i < 4; ++i) {
      float a = sA[(rg*4+i)*128 + kk];
      acc[i][0] = fmaf(a, wv.x, acc[i][0]);
      acc[i][1] = fmaf(a, wv.y, acc[i][1]);
      acc[i][2] = fmaf(a, wv.z, acc[i][2]);
      acc[i][3] = fmaf(a, wv.w, acc[i][3]);
    }
  }
  #pragma unroll
  for (int i = 0; i < 4; ++i) {
    int g = base + rg*4 + i;
    if (g < BN_)
      ((float4*)out)[(size_t)g*32 + cg] = make_float4(acc[i][0], acc[i][1], acc[i][2], acc[i][3]);
  }
}

extern "C" void kernel_launch(void* const* d_in, const int* in_sizes, int n_in,
                              void* d_out, int out_size, void* d_ws, size_t ws_size,
                              hipStream_t stream) {
  const float* q = (const float*)d_in[0];
  const float* w0 = (const float*)d_in[1];
  const float* w1 = (const float*)d_in[2];
  const float* w2 = (const float*)d_in[3];
  const float* w3 = (const float*)d_in[4];
  const float* w4 = (const float*)d_in[5];
  const float* w5 = (const float*)d_in[6];
  const float* w6 = (const float*)d_in[7];
  const float* w7 = (const float*)d_in[8];
  const float* w8 = (const float*)d_in[9];
  const float* wout = (const float*)d_in[10];
  float* out = (float*)d_out;

  char* ws = (char*)d_ws;
  unsigned short* qb  = (unsigned short*)(ws);                 // 8016*128*2   = 2,052,096
  unsigned short* wct = (unsigned short*)(ws + 2052096);       // 1152*128*2   =   294,912
  unsigned short* P   = (unsigned short*)(ws + 2347008);       // 72*16*501*16*2 = 18,468,864
  float* heads        = (float*)(ws + 20815872);               // 8016*128*4   = 4,104,192

  k_prep<<<dim3(4008), dim3(256), 0, stream>>>(q, w0,w1,w2,w3,w4,w5,w6,w7,w8, qb, wct);
  k_proj<<<dim3(18, 128), dim3(256), 0, stream>>>(qb, wct, P);
  k_attn<<<dim3(8, 16, 8), dim3(256), 0, stream>>>(P, heads);
  k_out<<<dim3(251), dim3(256), 0, stream>>>(heads, wout, out);
}

// Round 2
// 141.701 us; speedup vs baseline: 1.3048x; 1.3048x over previous
//
#include <hip/hip_runtime.h>

#define H_ 8
#define D_ 128
#define KD_ 16
#define E_ 128
#define B_ 16
#define G_ 501
#define NP_ 250
#define BN_ (B_*G_)   // 8016

typedef __bf16 bf16x8 __attribute__((ext_vector_type(8)));
typedef float f32x4 __attribute__((ext_vector_type(4)));
typedef unsigned short u16x8 __attribute__((ext_vector_type(8)));
// may_alias for LDS round-trips without a barrier (eBuf: written as u32, read as bf16x8)
typedef bf16x8 __attribute__((may_alias)) bf16x8_a;
typedef u16x8 __attribute__((may_alias)) u16x8_a;

__device__ __forceinline__ unsigned short f2bf(float f) {
  unsigned int u = __builtin_bit_cast(unsigned int, f);
  unsigned int r = u + 0x7FFFu + ((u >> 16) & 1u);
  return (unsigned short)(r >> 16);
}
__device__ __forceinline__ float bf2f(unsigned short u) {
  unsigned int v = ((unsigned int)u) << 16;
  return __builtin_bit_cast(float, v);
}
// permuted key position within its 32-key chunk: p = 2*i + t  (key = chunk + t*16 + i)
__device__ __forceinline__ int vpos(int key) {
  return (key & ~31) | ((key & 15) << 1) | ((key >> 4) & 1);
}

// ---------------- K0: cast q -> bf16, build WcT[c=(h,w,k)][d] bf16 ----------------
__global__ __launch_bounds__(256) void k_prep(
    const float* __restrict__ q,
    const float* __restrict__ w0, const float* __restrict__ w1, const float* __restrict__ w2,
    const float* __restrict__ w3, const float* __restrict__ w4, const float* __restrict__ w5,
    const float* __restrict__ w6, const float* __restrict__ w7, const float* __restrict__ w8,
    unsigned short* __restrict__ qb, unsigned short* __restrict__ wct) {
  int i = blockIdx.x * 256 + threadIdx.x;
  if (i < BN_*D_) qb[i] = f2bf(q[i]);
  if (i < H_*9*KD_*D_) {
    int d = i & 127; int t = i >> 7; int k = t & 15; t >>= 4;
    int wi = t % 9; int h = t / 9;
    const float* src = w0;
    switch (wi) {
      case 1: src = w1; break; case 2: src = w2; break; case 3: src = w3; break;
      case 4: src = w4; break; case 5: src = w5; break; case 6: src = w6; break;
      case 7: src = w7; break; case 8: src = w8; break; default: break;
    }
    wct[i] = f2bf(src[h*(D_*KD_) + d*KD_ + k]);
  }
}

// ---------------- K1: P[(h,w,b)][n][kd] = q @ Wcat, LDS-staged MFMA GEMM ----------
// grid (18, 128); block 256. Query-type projections (w != 1,2) pre-scaled by 0.25.
__global__ __launch_bounds__(256) void k_proj(const unsigned short* __restrict__ qb,
                                              const unsigned short* __restrict__ wct,
                                              unsigned short* __restrict__ P) {
  const int tid = threadIdx.x;
  const int lane = tid & 63;
  const int wv = tid >> 6;
  const int ln = lane & 15;
  const int quad = lane >> 4;
  const int b = blockIdx.y >> 3;
  const int nt = blockIdx.y & 7;
  const int cbase = blockIdx.x * 64;

  __shared__ __align__(16) unsigned short sA[64*136];
  __shared__ __align__(16) unsigned short sB[64*136];

  for (int i = tid; i < 1024; i += 256) {          // A: 64 rows x 128 d
    int rr = i >> 4, half = i & 15;
    int r = min(nt*64 + rr, G_ - 1);
    u16x8 v = *(const u16x8*)(qb + (size_t)(b*G_ + r)*D_ + half*8);
    *(u16x8*)(sA + rr*136 + half*8) = v;
  }
  for (int i = tid; i < 1024; i += 256) {          // B: 64 cols x 128 d
    int cc = i >> 4, half = i & 15;
    u16x8 v = *(const u16x8*)(wct + (size_t)(cbase + cc)*D_ + half*8);
    *(u16x8*)(sB + cc*136 + half*8) = v;
  }
  __syncthreads();

  bf16x8 a[4];
  #pragma unroll
  for (int ks = 0; ks < 4; ++ks)
    a[ks] = *(const bf16x8_a*)(sA + (wv*16 + ln)*136 + ks*32 + quad*8);

  #pragma unroll
  for (int ct = 0; ct < 4; ++ct) {
    f32x4 acc = {0.f,0.f,0.f,0.f};
    #pragma unroll
    for (int ks = 0; ks < 4; ++ks) {
      bf16x8 bb = *(const bf16x8_a*)(sB + (ct*16 + ln)*136 + ks*32 + quad*8);
      acc = __builtin_amdgcn_mfma_f32_16x16x32_bf16(a[ks], bb, acc, 0,0,0);
    }
    const int c = cbase + ct*16 + ln;
    const int h = c / 144; const int rem = c - h*144; const int w = rem >> 4; const int k = rem & 15;
    const float sc = (w == 1 || w == 2) ? 1.0f : 0.25f;   // fold norm=1/sqrt(KD) into Q-type
    const size_t pb = ((size_t)((h*9 + w)*B_ + b)*G_)*KD_ + k;
    #pragma unroll
    for (int g = 0; g < 4; ++g) {
      const int nn = nt*64 + wv*16 + quad*4 + g;
      if (nn < G_) P[pb + (size_t)nn*KD_] = f2bf(acc[g]*sc);
    }
  }
}

// ---------------- K2: fused heterogeneous attention (MFMA PV) ----------------
// grid = (rt=8, b=16, h=8); block 256 (4 waves x 16 rows). 3 blocks/CU.
template<bool UP, bool UD>
__device__ __forceinline__ void attn_chunk(
    int c, const unsigned short* sK, const unsigned short* sVt, unsigned int* myE,
    bf16x8 aQa, bf16x8 aQp, bf16x8 aQd,
    const float* rv, float* esum, f32x4& acc, int ln, int quad)
{
  const f32x4 z4 = {0.f,0.f,0.f,0.f};
  const unsigned short* kb = sK + c*512 + ln*16 + quad*8;
  bf16x8 bk0 = *(const bf16x8_a*)(kb);
  bf16x8 bk1 = *(const bf16x8_a*)(kb + 256);
  f32x4 sa0 = __builtin_amdgcn_mfma_f32_16x16x32_bf16(aQa, bk0, z4, 0,0,0);
  f32x4 sa1 = __builtin_amdgcn_mfma_f32_16x16x32_bf16(aQa, bk1, z4, 0,0,0);
  f32x4 sp0 = z4, sp1 = z4, sd0 = z4, sd1 = z4;
  if (UP) {
    sp0 = __builtin_amdgcn_mfma_f32_16x16x32_bf16(aQp, bk0, z4, 0,0,0);
    sp1 = __builtin_amdgcn_mfma_f32_16x16x32_bf16(aQp, bk1, z4, 0,0,0);
  }
  if (UD) {
    sd0 = __builtin_amdgcn_mfma_f32_16x16x32_bf16(aQd, bk0, z4, 0,0,0);
    sd1 = __builtin_amdgcn_mfma_f32_16x16x32_bf16(aQd, bk1, z4, 0,0,0);
  }
  const int k0 = c*32 + ln, k1 = k0 + 16;     // k0 <= 495, always a valid "comp" key
  const float am1 = (k1 <= 500) ? 1.f : 0.f;
  const float pm0 = (k0 >= 1 && k0 <= 250) ? 1.f : 0.f;
  const float pm1 = (k1 <= 250) ? 1.f : 0.f;
  const float dm0 = (k0 >= 251) ? 1.f : 0.f;
  const float dm1 = (k1 >= 251 && k1 <= 500) ? 1.f : 0.f;
  #pragma unroll
  for (int g = 0; g < 4; ++g) {
    float e0 = __expf(sa0[g]);
    float e1 = am1 * __expf(sa1[g]);
    float x0 = 0.f, x1 = 0.f;
    if (UP) { x0 += pm0*__expf(sp0[g]); x1 += pm1*__expf(sp1[g]); }
    if (UD) { x0 += dm0*__expf(sd0[g]); x1 += dm1*__expf(sd1[g]); }
    e0 += rv[g]*x0; e1 += rv[g]*x1;
    esum[g] += e0 + e1;
    myE[(quad*4 + g)*20 + ln] = (unsigned)f2bf(e0) | ((unsigned)f2bf(e1) << 16);
  }
  bf16x8 Ef = *(const bf16x8_a*)((const unsigned short*)myE + ln*40 + quad*8);
  bf16x8 Vf = *(const bf16x8_a*)(sVt + ln*520 + c*32 + quad*8);
  acc = __builtin_amdgcn_mfma_f32_16x16x32_bf16(Ef, Vf, acc, 0,0,0);
}

__global__ __launch_bounds__(256, 3) void k_attn(const unsigned short* __restrict__ P,
                                                 float* __restrict__ heads) {
  const int rt = blockIdx.x, b = blockIdx.y, h = blockIdx.z;
  const int tid = threadIdx.x;
  const int lane = tid & 63;
  const int wv = tid >> 6;
  const int ln = lane & 15;
  const int quad = lane >> 4;
  const int r0 = rt * 64;

  __shared__ __align__(16) unsigned short sK [513*16];  // [key][kd], row 512 = 0
  __shared__ __align__(16) unsigned short sVt[16*520];  // [kd][pos], permuted key order
  __shared__ __align__(16) unsigned short sQa[65*16];
  __shared__ __align__(16) unsigned short sQp[65*16];
  __shared__ __align__(16) unsigned short sQd[65*16];
  __shared__ __align__(16) unsigned short sQs[65*16];
  __shared__ __align__(16) unsigned short sKs[65*16];   // K row of each query's paired key
  __shared__ __align__(16) unsigned int   eBuf[4*16*20]; // per-wave E transpose buffer

  const size_t slab = (size_t)G_*KD_;
  const unsigned short* Pk = P + ((size_t)(h*9+1)*B_ + b)*slab;
  const unsigned short* Pv = P + ((size_t)(h*9+2)*B_ + b)*slab;
  const u16x8 vz = {0,0,0,0,0,0,0,0};

  for (int i = tid; i < 1026; i += 256) {      // sK: 513 rows x 16 (two 8-short halves)
    int key = i >> 1;
    u16x8 v = vz;
    if (key < G_) v = *(const u16x8*)(Pk + key*KD_ + (i & 1)*8);
    *(u16x8*)(sK + i*8) = v;
  }
  for (int i = tid; i < 8192; i += 256) {      // sVt: scatter into permuted layout
    int key = i >> 4, kd = i & 15;
    unsigned short v = (key < G_) ? Pv[key*KD_ + kd] : (unsigned short)0;
    sVt[kd*520 + vpos(key)] = v;
  }
  for (int i = tid; i < 650; i += 256) {       // sQa/sQp/sQd/sQs/sKs: 5 arrays x 130 chunks
    int arr = i / 130;
    int j = i - arr*130;
    int rr = j >> 1, half = j & 1;
    int r = r0 + rr;
    u16x8 v = vz;
    if (rr < 64 && r < G_) {
      bool pick = (r <= NP_);
      const unsigned short* src;
      if (arr == 4) {
        int ks = (r == 0) ? 0 : (pick ? r + NP_ : r - NP_);
        src = Pk + ks*KD_;
      } else {
        int w = (arr == 0) ? 0 : (arr == 1) ? (pick ? 4 : 8)
              : (arr == 2) ? (pick ? 5 : 7) : (pick ? 3 : 6);
        src = P + ((size_t)(h*9 + w)*B_ + b)*slab + (size_t)r*KD_;
      }
      v = *(const u16x8*)(src + half*8);
    }
    unsigned short* dst = (arr==0) ? sQa : (arr==1) ? sQp : (arr==2) ? sQd
                        : (arr==3) ? sQs : sKs;
    *(u16x8*)(dst + j*8) = v;
  }
  __syncthreads();

  // Q A-fragments (K=32, kd 16..31 must be zero -> zero quads 2,3 entirely)
  const int aoff = (wv*16 + ln)*16 + quad*8;
  bf16x8 aQa = *(const bf16x8_a*)(sQa + aoff);
  bf16x8 aQp = *(const bf16x8_a*)(sQp + aoff);
  bf16x8 aQd = *(const bf16x8_a*)(sQd + aoff);
  bf16x8 aQs = *(const bf16x8_a*)(sQs + aoff);
  if (quad >= 2) {
    bf16x8 zb = {};
    aQa = zb; aQp = zb; aQd = zb; aQs = zb;
  }

  const int rw0 = r0 + wv*16;
  float rv[4], rvs[4]; int posks[4];
  #pragma unroll
  for (int g = 0; g < 4; ++g) {
    int ra = rw0 + quad*4 + g;
    rv[g]  = (ra >= 1) ? 1.f : 0.f;
    rvs[g] = (ra >= 1 && ra < G_) ? 1.f : 0.f;
    int ks = (ra >= 1) ? ((ra <= NP_) ? ra + NP_ : ra - NP_) : 0;
    posks[g] = vpos(ks);
  }

  f32x4 acc = {0.f,0.f,0.f,0.f};
  float esum[4] = {0.f,0.f,0.f,0.f};
  unsigned int* myE = eBuf + wv*320;

  for (int c = 0; c < 7; ++c)
    attn_chunk<true,false>(c, sK, sVt, myE, aQa, aQp, aQd, rv, esum, acc, ln, quad);
  attn_chunk<true,true>(7, sK, sVt, myE, aQa, aQp, aQd, rv, esum, acc, ln, quad);
  for (int c = 8; c < 16; ++c)
    attn_chunk<false,true>(c, sK, sVt, myE, aQa, aQp, aQd, rv, esum, acc, ln, quad);

  // paired single score: one MFMA, take the diagonal
  const f32x4 z4 = {0.f,0.f,0.f,0.f};
  bf16x8 bks = *(const bf16x8_a*)(sKs + aoff);
  f32x4 ss = __builtin_amdgcn_mfma_f32_16x16x32_bf16(aQs, bks, z4, 0,0,0);
  float es[4];
  #pragma unroll
  for (int g = 0; g < 4; ++g) {
    float v = __shfl(ss[g], quad*16 + quad*4 + g, 64);
    es[g] = rvs[g] * __expf(v);
  }
  #pragma unroll
  for (int g = 0; g < 4; ++g) {
    float t = esum[g];
    t += __shfl_xor(t, 1); t += __shfl_xor(t, 2);
    t += __shfl_xor(t, 4); t += __shfl_xor(t, 8);
    esum[g] = t + es[g];
  }
  #pragma unroll
  for (int g = 0; g < 4; ++g) {
    int ra = rw0 + quad*4 + g;
    float o = acc[g] + es[g] * bf2f(sVt[ln*520 + posks[g]]);
    if (ra < G_)
      heads[((size_t)(b*G_ + ra))*E_ + h*16 + ln] = o * __builtin_amdgcn_rcpf(esum[g]);
  }
}

// ---------------- K3: out = heads(8016x128) @ W_out(128x128), fp32 ----------------
// grid 501 blocks x 256 thr; 16 rows per block.
__global__ __launch_bounds__(256) void k_out(const float* __restrict__ heads,
                                             const float* __restrict__ wout,
                                             float* __restrict__ out) {
  const int base = blockIdx.x * 16;
  const int tid = threadIdx.x;
  __shared__ __align__(16) float sA[16*128];
  for (int i = tid; i < 512; i += 256)
    ((float4*)sA)[i] = ((const float4*)heads)[(size_t)base*32 + i];
  __syncthreads();
  const int cg = tid & 31, rh = tid >> 5;     // rh 0..7 -> rows rh*2, rh*2+1
  float4 acc0 = make_float4(0.f,0.f,0.f,0.f);
  float4 acc1 = make_float4(0.f,0.f,0.f,0.f);
  const float4* w4 = (const float4*)wout;
  #pragma unroll 8
  for (int kk = 0; kk < 128; ++kk) {
    float4 wv = w4[kk*32 + cg];
    float a0 = sA[(rh*2)*128 + kk];
    float a1 = sA[(rh*2+1)*128 + kk];
    acc0.x = fmaf(a0, wv.x, acc0.x); acc0.y = fmaf(a0, wv.y, acc0.y);
    acc0.z = fmaf(a0, wv.z, acc0.z); acc0.w = fmaf(a0, wv.w, acc0.w);
    acc1.x = fmaf(a1, wv.x, acc1.x); acc1.y = fmaf(a1, wv.y, acc1.y);
    acc1.z = fmaf(a1, wv.z, acc1.z); acc1.w = fmaf(a1, wv.w, acc1.w);
  }
  ((float4*)out)[(size_t)(base + rh*2)*32 + cg] = acc0;
  ((float4*)out)[(size_t)(base + rh*2 + 1)*32 + cg] = acc1;
}

extern "C" void kernel_launch(void* const* d_in, const int* in_sizes, int n_in,
                              void* d_out, int out_size, void* d_ws, size_t ws_size,
                              hipStream_t stream) {
  const float* q = (const float*)d_in[0];
  const float* w0 = (const float*)d_in[1];
  const float* w1 = (const float*)d_in[2];
  const float* w2 = (const float*)d_in[3];
  const float* w3 = (const float*)d_in[4];
  const float* w4 = (const float*)d_in[5];
  const float* w5 = (const float*)d_in[6];
  const float* w6 = (const float*)d_in[7];
  const float* w7 = (const float*)d_in[8];
  const float* w8 = (const float*)d_in[9];
  const float* wout = (const float*)d_in[10];
  float* out = (float*)d_out;

  char* ws = (char*)d_ws;
  unsigned short* qb  = (unsigned short*)(ws);                 // 8016*128*2   = 2,052,096
  unsigned short* wct = (unsigned short*)(ws + 2052096);       // 1152*128*2   =   294,912
  unsigned short* P   = (unsigned short*)(ws + 2347008);       // 72*16*501*16*2 = 18,468,864
  float* heads        = (float*)(ws + 20815872);               // 8016*128*4   = 4,104,192

  k_prep<<<dim3(4008), dim3(256), 0, stream>>>(q, w0,w1,w2,w3,w4,w5,w6,w7,w8, qb, wct);
  k_proj<<<dim3(18, 128), dim3(256), 0, stream>>>(qb, wct, P);
  k_attn<<<dim3(8, 16, 8), dim3(256), 0, stream>>>(P, heads);
  k_out<<<dim3(501), dim3(256), 0, stream>>>(heads, wout, out);
}